// Round 1
// baseline (2929.932 us; speedup 1.0000x reference)
//
#include <hip/hip_runtime.h>

// GCNConv (self-loops, symmetric norm) + bias + PReLU, fp32.
// out[d] = prelu( dis[d] * ( sum_{e: dst=d} h[src_e]*dis[src_e] + h[d]*dis[d] ) + b )
// where h = x @ W, dis = rsqrt(in_degree + 1).

constexpr int N_NODES = 100000;
constexpr int N_EDGES = 1600000;
constexpr int C = 128;       // in/out channels
constexpr int BM = 32;       // GEMM row tile (100000 % 32 == 0 -> 3125 blocks, no tail)

__global__ __launch_bounds__(256) void k_init_deg(float* __restrict__ deg) {
    int i = blockIdx.x * 256 + threadIdx.x;
    if (i < N_NODES) deg[i] = 1.0f;   // self-loop
}

__global__ __launch_bounds__(256) void k_count(const int* __restrict__ dst,
                                               float* __restrict__ deg) {
    int e = blockIdx.x * 256 + threadIdx.x;
    if (e < N_EDGES) atomicAdd(&deg[dst[e]], 1.0f);
}

__global__ __launch_bounds__(256) void k_rsqrt(float* __restrict__ deg) {
    int i = blockIdx.x * 256 + threadIdx.x;
    if (i < N_NODES) deg[i] = rsqrtf(deg[i]);
}

// hs[r][:] = (x[r][:] @ W) * dis[r]; also seed out with the same value
// (self-loop contribution before the final dis[d] post-scale).
__global__ __launch_bounds__(256) void k_gemm(const float* __restrict__ x,
                                              const float* __restrict__ W,
                                              const float* __restrict__ dis,
                                              float* __restrict__ hs,
                                              float* __restrict__ out) {
    __shared__ float Ws[C * C];   // 64 KiB, [k][j] row-major (same as W)
    __shared__ float xs[BM * C];  // 16 KiB, [r][k] row-major

    const int t = threadIdx.x;
    {
        const float4* W4 = (const float4*)W;
        float4* Ws4 = (float4*)Ws;
#pragma unroll
        for (int i = 0; i < 16; ++i) Ws4[i * 256 + t] = W4[i * 256 + t];
    }
    const int row0 = blockIdx.x * BM;
    {
        const float4* x4 = (const float4*)(x + (size_t)row0 * C);
        float4* xs4 = (float4*)xs;
#pragma unroll
        for (int i = 0; i < 4; ++i) xs4[i * 256 + t] = x4[i * 256 + t];
    }
    __syncthreads();

    const int cg4 = (t & 31) * 4;   // 4 output cols
    const int rg4 = (t >> 5) * 4;   // 4 rows
    float acc[4][4] = {};

#pragma unroll 4
    for (int k4 = 0; k4 < C; k4 += 4) {
        float4 xv[4], wv[4];
#pragma unroll
        for (int i = 0; i < 4; ++i) xv[i] = *(const float4*)&xs[(rg4 + i) * C + k4];
#pragma unroll
        for (int kk = 0; kk < 4; ++kk) wv[kk] = *(const float4*)&Ws[(k4 + kk) * C + cg4];
#pragma unroll
        for (int i = 0; i < 4; ++i) {
            const float* xvf = (const float*)&xv[i];
#pragma unroll
            for (int kk = 0; kk < 4; ++kk) {
                acc[i][0] = fmaf(xvf[kk], wv[kk].x, acc[i][0]);
                acc[i][1] = fmaf(xvf[kk], wv[kk].y, acc[i][1]);
                acc[i][2] = fmaf(xvf[kk], wv[kk].z, acc[i][2]);
                acc[i][3] = fmaf(xvf[kk], wv[kk].w, acc[i][3]);
            }
        }
    }

#pragma unroll
    for (int i = 0; i < 4; ++i) {
        const int r = row0 + rg4 + i;
        const float s = dis[r];
        float4 v;
        v.x = acc[i][0] * s; v.y = acc[i][1] * s;
        v.z = acc[i][2] * s; v.w = acc[i][3] * s;
        *(float4*)&hs[(size_t)r * C + cg4] = v;
        *(float4*)&out[(size_t)r * C + cg4] = v;   // self-loop seed
    }
}

// 32 threads per edge, 4 cols each: out[d][c] += hs[s][c]
__global__ __launch_bounds__(256) void k_scatter(const int* __restrict__ src,
                                                 const int* __restrict__ dst,
                                                 const float* __restrict__ hs,
                                                 float* __restrict__ out) {
    int gid = blockIdx.x * 256 + threadIdx.x;
    int e  = gid >> 5;
    int c4 = (gid & 31) << 2;
    if (e < N_EDGES) {
        int s = src[e], d = dst[e];
        float4 v = *(const float4*)&hs[s * C + c4];
        float* o = &out[d * C + c4];
        atomicAdd(o + 0, v.x);
        atomicAdd(o + 1, v.y);
        atomicAdd(o + 2, v.z);
        atomicAdd(o + 3, v.w);
    }
}

__global__ __launch_bounds__(256) void k_final(float* __restrict__ out,
                                               const float* __restrict__ dis,
                                               const float* __restrict__ b,
                                               const float* __restrict__ alpha) {
    int gid = blockIdx.x * 256 + threadIdx.x;   // one float4 each
    int i  = gid >> 5;
    int c4 = (gid & 31) << 2;
    if (i < N_NODES) {
        const float a = alpha[0];
        const float s = dis[i];
        float4 v = *(float4*)&out[i * C + c4];
        float4 bv = *(const float4*)&b[c4];
        float t0 = fmaf(v.x, s, bv.x);
        float t1 = fmaf(v.y, s, bv.y);
        float t2 = fmaf(v.z, s, bv.z);
        float t3 = fmaf(v.w, s, bv.w);
        float4 r;
        r.x = t0 >= 0.f ? t0 : a * t0;
        r.y = t1 >= 0.f ? t1 : a * t1;
        r.z = t2 >= 0.f ? t2 : a * t2;
        r.w = t3 >= 0.f ? t3 : a * t3;
        *(float4*)&out[i * C + c4] = r;
    }
}

extern "C" void kernel_launch(void* const* d_in, const int* in_sizes, int n_in,
                              void* d_out, int out_size, void* d_ws, size_t ws_size,
                              hipStream_t stream) {
    const float* x     = (const float*)d_in[0];
    const int*   ei    = (const int*)d_in[1];     // [2][E] flat: row0=src, row1=dst
    const float* W     = (const float*)d_in[2];
    const float* b     = (const float*)d_in[3];
    const float* alpha = (const float*)d_in[4];
    float* out = (float*)d_out;

    float* deg = (float*)d_ws;                 // N floats (becomes dis after rsqrt)
    float* hs  = deg + N_NODES;                // N*C floats (51.2 MB)

    const int* src = ei;
    const int* dst = ei + N_EDGES;

    k_init_deg<<<(N_NODES + 255) / 256, 256, 0, stream>>>(deg);
    k_count<<<(N_EDGES + 255) / 256, 256, 0, stream>>>(dst, deg);
    k_rsqrt<<<(N_NODES + 255) / 256, 256, 0, stream>>>(deg);
    k_gemm<<<N_NODES / BM, 256, 0, stream>>>(x, W, deg, hs, out);
    k_scatter<<<(N_EDGES * 32) / 256, 256, 0, stream>>>(src, dst, hs, out);
    k_final<<<(N_NODES * C / 4 + 255) / 256, 256, 0, stream>>>(out, deg, b, alpha);
}

// Round 9
// 473.936 us; speedup vs baseline: 6.1821x; 6.1821x over previous
//
#include <hip/hip_runtime.h>

// GCNConv (self-loops, symmetric norm) + bias + PReLU, fp32.
// out[d] = prelu( dis[d] * ( sum_{e: dst=d} hs[src_e] + hs[d] ) + b )
// where hs = (x @ W) * dis[row], dis = rsqrt(in_degree + 1).
// Aggregation via CSR gather (counting sort by dst) -- no fp32 atomics.

constexpr int N_NODES = 100000;
constexpr int N_EDGES = 1600000;
constexpr int C  = 128;
constexpr int BM = 32;                       // GEMM row tile
constexpr int SCAN_B  = 256;
constexpr int N_BLKS  = (N_NODES + SCAN_B - 1) / SCAN_B;   // 391

__global__ __launch_bounds__(256) void k_zero(int* __restrict__ cnt) {
    int i = blockIdx.x * 256 + threadIdx.x;
    if (i < N_NODES) cnt[i] = 0;
}

__global__ __launch_bounds__(256) void k_count(const int* __restrict__ dst,
                                               int* __restrict__ cnt) {
    int e = blockIdx.x * 256 + threadIdx.x;
    if (e < N_EDGES) atomicAdd(&cnt[dst[e]], 1);
}

// block-local exclusive scan of cnt -> rowptr, per-block totals -> bsum
__global__ __launch_bounds__(SCAN_B) void k_scan1(const int* __restrict__ cnt,
                                                  int* __restrict__ rowptr,
                                                  int* __restrict__ bsum) {
    __shared__ int s[SCAN_B];
    int t = threadIdx.x;
    int i = blockIdx.x * SCAN_B + t;
    int v = (i < N_NODES) ? cnt[i] : 0;
    s[t] = v;
    __syncthreads();
#pragma unroll
    for (int off = 1; off < SCAN_B; off <<= 1) {
        int u = (t >= off) ? s[t - off] : 0;
        __syncthreads();
        s[t] += u;
        __syncthreads();
    }
    if (i < N_NODES) rowptr[i] = s[t] - v;          // exclusive
    if (t == SCAN_B - 1) bsum[blockIdx.x] = s[t];   // block total
}

// single-block exclusive scan of the 391 block totals
__global__ __launch_bounds__(512) void k_scan2(int* __restrict__ bsum) {
    __shared__ int s[512];
    int t = threadIdx.x;
    int v = (t < N_BLKS) ? bsum[t] : 0;
    s[t] = v;
    __syncthreads();
#pragma unroll
    for (int off = 1; off < 512; off <<= 1) {
        int u = (t >= off) ? s[t - off] : 0;
        __syncthreads();
        s[t] += u;
        __syncthreads();
    }
    if (t < N_BLKS) bsum[t] = s[t] - v;             // exclusive
}

// add block offsets; init cursor; rowptr[N]=E; dis = rsqrt(cnt+1)
__global__ __launch_bounds__(SCAN_B) void k_scan3(int* __restrict__ rowptr,
                                                  const int* __restrict__ bsum,
                                                  int* __restrict__ cursor,
                                                  const int* __restrict__ cnt,
                                                  float* __restrict__ dis) {
    int i = blockIdx.x * SCAN_B + threadIdx.x;
    if (i < N_NODES) {
        int r = rowptr[i] + bsum[blockIdx.x];
        rowptr[i] = r;
        cursor[i] = r;
        dis[i] = rsqrtf((float)(cnt[i] + 1));
    }
    if (i == 0) rowptr[N_NODES] = N_EDGES;
}

__global__ __launch_bounds__(256) void k_fill(const int* __restrict__ src,
                                              const int* __restrict__ dst,
                                              int* __restrict__ cursor,
                                              int* __restrict__ adj) {
    int e = blockIdx.x * 256 + threadIdx.x;
    if (e < N_EDGES) {
        int pos = atomicAdd(&cursor[dst[e]], 1);
        adj[pos] = src[e];
    }
}

// hs[r][:] = (x[r][:] @ W) * dis[r]
__global__ __launch_bounds__(256) void k_gemm(const float* __restrict__ x,
                                              const float* __restrict__ W,
                                              const float* __restrict__ dis,
                                              float* __restrict__ hs) {
    __shared__ float Ws[C * C];   // 64 KiB, [k][j]
    __shared__ float xs[BM * C];  // 16 KiB, [r][k]

    const int t = threadIdx.x;
    {
        const float4* W4 = (const float4*)W;
        float4* Ws4 = (float4*)Ws;
#pragma unroll
        for (int i = 0; i < 16; ++i) Ws4[i * 256 + t] = W4[i * 256 + t];
    }
    const int row0 = blockIdx.x * BM;
    {
        const float4* x4 = (const float4*)(x + (size_t)row0 * C);
        float4* xs4 = (float4*)xs;
#pragma unroll
        for (int i = 0; i < 4; ++i) xs4[i * 256 + t] = x4[i * 256 + t];
    }
    __syncthreads();

    const int cg4 = (t & 31) * 4;
    const int rg4 = (t >> 5) * 4;
    float acc[4][4] = {};

#pragma unroll 4
    for (int k4 = 0; k4 < C; k4 += 4) {
        float4 xv[4], wv[4];
#pragma unroll
        for (int i = 0; i < 4; ++i) xv[i] = *(const float4*)&xs[(rg4 + i) * C + k4];
#pragma unroll
        for (int kk = 0; kk < 4; ++kk) wv[kk] = *(const float4*)&Ws[(k4 + kk) * C + cg4];
#pragma unroll
        for (int i = 0; i < 4; ++i) {
            const float* xvf = (const float*)&xv[i];
#pragma unroll
            for (int kk = 0; kk < 4; ++kk) {
                acc[i][0] = fmaf(xvf[kk], wv[kk].x, acc[i][0]);
                acc[i][1] = fmaf(xvf[kk], wv[kk].y, acc[i][1]);
                acc[i][2] = fmaf(xvf[kk], wv[kk].z, acc[i][2]);
                acc[i][3] = fmaf(xvf[kk], wv[kk].w, acc[i][3]);
            }
        }
    }

#pragma unroll
    for (int i = 0; i < 4; ++i) {
        const int r = row0 + rg4 + i;
        const float s = dis[r];
        float4 v;
        v.x = acc[i][0] * s; v.y = acc[i][1] * s;
        v.z = acc[i][2] * s; v.w = acc[i][3] * s;
        *(float4*)&hs[(size_t)r * C + cg4] = v;
    }
}

// one wave per node; lane owns 2 columns (float2). Fused epilogue.
__global__ __launch_bounds__(256) void k_gather(const int* __restrict__ rowptr,
                                                const int* __restrict__ adj,
                                                const float* __restrict__ hs,
                                                const float* __restrict__ dis,
                                                const float* __restrict__ b,
                                                const float* __restrict__ alpha,
                                                float* __restrict__ out) {
    const int wave = (blockIdx.x * 256 + threadIdx.x) >> 6;
    const int lane = threadIdx.x & 63;
    if (wave >= N_NODES) return;
    const int d = wave;
    const int beg = rowptr[d], end = rowptr[d + 1];
    const int co = lane * 2;

    float2 acc = *(const float2*)&hs[(size_t)d * C + co];   // self-loop term
    int j = beg;
    for (; j + 1 < end; j += 2) {
        int s0 = adj[j], s1 = adj[j + 1];
        float2 v0 = *(const float2*)&hs[(size_t)s0 * C + co];
        float2 v1 = *(const float2*)&hs[(size_t)s1 * C + co];
        acc.x += v0.x; acc.y += v0.y;
        acc.x += v1.x; acc.y += v1.y;
    }
    if (j < end) {
        int s0 = adj[j];
        float2 v0 = *(const float2*)&hs[(size_t)s0 * C + co];
        acc.x += v0.x; acc.y += v0.y;
    }

    const float sd = dis[d];
    const float a  = alpha[0];
    float2 bv = *(const float2*)&b[co];
    float t0 = fmaf(acc.x, sd, bv.x);
    float t1 = fmaf(acc.y, sd, bv.y);
    float2 r;
    r.x = t0 >= 0.f ? t0 : a * t0;
    r.y = t1 >= 0.f ? t1 : a * t1;
    *(float2*)&out[(size_t)d * C + co] = r;
}

extern "C" void kernel_launch(void* const* d_in, const int* in_sizes, int n_in,
                              void* d_out, int out_size, void* d_ws, size_t ws_size,
                              hipStream_t stream) {
    const float* x     = (const float*)d_in[0];
    const int*   ei    = (const int*)d_in[1];     // [2][E] flat: row0=src, row1=dst
    const float* W     = (const float*)d_in[2];
    const float* b     = (const float*)d_in[3];
    const float* alpha = (const float*)d_in[4];
    float* out = (float*)d_out;

    const int* src = ei;
    const int* dst = ei + N_EDGES;

    // workspace layout
    char* p = (char*)d_ws;
    int*   cnt    = (int*)p;                 p += sizeof(int) * N_NODES;
    int*   rowptr = (int*)p;                 p += sizeof(int) * (N_NODES + 1);
    int*   cursor = (int*)p;                 p += sizeof(int) * N_NODES;
    int*   bsum   = (int*)p;                 p += sizeof(int) * 512;
    float* dis    = (float*)p;               p += sizeof(float) * N_NODES;
    int*   adj    = (int*)p;                 p += sizeof(int) * N_EDGES;
    float* hs     = (float*)p;               // N*C floats (51.2 MB)

    const int gN = (N_NODES + 255) / 256;
    const int gE = (N_EDGES + 255) / 256;

    k_zero <<<gN, 256, 0, stream>>>(cnt);
    k_count<<<gE, 256, 0, stream>>>(dst, cnt);
    k_scan1<<<N_BLKS, SCAN_B, 0, stream>>>(cnt, rowptr, bsum);
    k_scan2<<<1, 512, 0, stream>>>(bsum);
    k_scan3<<<N_BLKS, SCAN_B, 0, stream>>>(rowptr, bsum, cursor, cnt, dis);
    k_fill <<<gE, 256, 0, stream>>>(src, dst, cursor, adj);
    k_gemm <<<N_NODES / BM, 256, 0, stream>>>(x, W, dis, hs);
    k_gather<<<(N_NODES * 64 + 255) / 256, 256, 0, stream>>>(rowptr, adj, hs, dis, b, alpha, out);
}

// Round 10
// 385.295 us; speedup vs baseline: 7.6044x; 1.2301x over previous
//
#include <hip/hip_runtime.h>

// GCNConv (self-loops, symmetric norm) + bias + PReLU.
// out[d] = prelu( dis[d] * ( sum_{e: dst=d} hs[src_e] + hs[d] ) + b )
// hs = bf16( (x @ W) * dis[row] ) computed via MFMA bf16; dis = rsqrt(deg+1).
// Aggregation via CSR gather (counting sort by dst) -- no fp32 atomics.

constexpr int N_NODES = 100000;
constexpr int N_EDGES = 1600000;
constexpr int C  = 128;
constexpr int BM = 32;                       // GEMM row tile (100000 % 32 == 0)
constexpr int SCAN_B  = 256;
constexpr int N_BLKS  = (N_NODES + SCAN_B - 1) / SCAN_B;   // 391

using f32x4 = __attribute__((ext_vector_type(4))) float;
using s16x8 = __attribute__((ext_vector_type(8))) short;   // 8 bf16 = 4 VGPRs

// round-to-nearest-even fp32 -> bf16 (bit trick; inputs are finite)
__device__ __forceinline__ unsigned short f2bf(float f) {
    unsigned int u = __float_as_uint(f);
    u += 0x7fffu + ((u >> 16) & 1u);
    return (unsigned short)(u >> 16);
}

__global__ __launch_bounds__(256) void k_zero(int* __restrict__ cnt) {
    int i = blockIdx.x * 256 + threadIdx.x;
    if (i < N_NODES) cnt[i] = 0;
}

__global__ __launch_bounds__(256) void k_count(const int* __restrict__ dst,
                                               int* __restrict__ cnt) {
    int e = blockIdx.x * 256 + threadIdx.x;
    if (e < N_EDGES) atomicAdd(&cnt[dst[e]], 1);
}

// Wt[j][k] = bf16(W[k][j])  (transpose + quantize, 16384 elems)
__global__ __launch_bounds__(256) void k_prep(const float* __restrict__ W,
                                              unsigned short* __restrict__ Wt) {
    int tid = blockIdx.x * 256 + threadIdx.x;   // 64 blocks x 256 = 16384
    int k = tid & 127;
    int j = tid >> 7;
    Wt[j * 128 + k] = f2bf(W[k * 128 + j]);
}

// block-local exclusive scan of cnt -> rowptr, per-block totals -> bsum
__global__ __launch_bounds__(SCAN_B) void k_scan1(const int* __restrict__ cnt,
                                                  int* __restrict__ rowptr,
                                                  int* __restrict__ bsum) {
    __shared__ int s[SCAN_B];
    int t = threadIdx.x;
    int i = blockIdx.x * SCAN_B + t;
    int v = (i < N_NODES) ? cnt[i] : 0;
    s[t] = v;
    __syncthreads();
#pragma unroll
    for (int off = 1; off < SCAN_B; off <<= 1) {
        int u = (t >= off) ? s[t - off] : 0;
        __syncthreads();
        s[t] += u;
        __syncthreads();
    }
    if (i < N_NODES) rowptr[i] = s[t] - v;          // exclusive
    if (t == SCAN_B - 1) bsum[blockIdx.x] = s[t];   // block total
}

__global__ __launch_bounds__(512) void k_scan2(int* __restrict__ bsum) {
    __shared__ int s[512];
    int t = threadIdx.x;
    int v = (t < N_BLKS) ? bsum[t] : 0;
    s[t] = v;
    __syncthreads();
#pragma unroll
    for (int off = 1; off < 512; off <<= 1) {
        int u = (t >= off) ? s[t - off] : 0;
        __syncthreads();
        s[t] += u;
        __syncthreads();
    }
    if (t < N_BLKS) bsum[t] = s[t] - v;             // exclusive
}

__global__ __launch_bounds__(SCAN_B) void k_scan3(int* __restrict__ rowptr,
                                                  const int* __restrict__ bsum,
                                                  int* __restrict__ cursor,
                                                  const int* __restrict__ cnt,
                                                  float* __restrict__ dis) {
    int i = blockIdx.x * SCAN_B + threadIdx.x;
    if (i < N_NODES) {
        int r = rowptr[i] + bsum[blockIdx.x];
        rowptr[i] = r;
        cursor[i] = r;
        dis[i] = rsqrtf((float)(cnt[i] + 1));
    }
    if (i == 0) rowptr[N_NODES] = N_EDGES;
}

__global__ __launch_bounds__(256) void k_fill(const int* __restrict__ src,
                                              const int* __restrict__ dst,
                                              int* __restrict__ cursor,
                                              int* __restrict__ adj) {
    int e = blockIdx.x * 256 + threadIdx.x;
    if (e < N_EDGES) {
        int pos = atomicAdd(&cursor[dst[e]], 1);
        adj[pos] = src[e];
    }
}

// hs[r][:] = bf16( (x[r][:] @ W) * dis[r] ), MFMA 16x16x32 bf16.
// 128 threads = 2 waves; each wave computes 16 rows x 128 cols.
__global__ __launch_bounds__(128) void k_gemm(const float* __restrict__ x,
                                              const unsigned short* __restrict__ Wt,
                                              const float* __restrict__ dis,
                                              unsigned short* __restrict__ hs) {
    // W^T in LDS, XOR-swizzled (row stride 256B; swz byte ^= (row&7)<<4)
    __shared__ __align__(16) unsigned short wlds[128 * 128];  // 32 KiB
    // x tile bf16, row stride 136 shorts (272B, +16B pad breaks bank aliasing)
    __shared__ __align__(16) unsigned short xlds[BM * 136];   // 8.5 KiB

    const int t = threadIdx.x;
    {   // stage Wt: 2048 x 16B chunks, coalesced reads, swizzled LDS writes
        const ulonglong2* srcp = (const ulonglong2*)Wt;
#pragma unroll
        for (int i = 0; i < 16; ++i) {
            int c = i * 128 + t;
            int byte = c << 4;
            int row = byte >> 8;
            int dstb = byte ^ ((row & 7) << 4);
            *(ulonglong2*)((char*)wlds + dstb) = srcp[c];
        }
    }
    const int row0 = blockIdx.x * BM;
    {   // stage x: 1024 float4 chunks, convert fp32->bf16, padded rows
        const float4* xs4 = (const float4*)(x + (size_t)row0 * C);
#pragma unroll
        for (int i = 0; i < 8; ++i) {
            int c = i * 128 + t;
            float4 v = xs4[c];
            int row = c >> 5;          // 32 float4 per row
            int k4  = (c & 31) << 2;
            unsigned long long pk =
                  (unsigned long long)f2bf(v.x)
                | ((unsigned long long)f2bf(v.y) << 16)
                | ((unsigned long long)f2bf(v.z) << 32)
                | ((unsigned long long)f2bf(v.w) << 48);
            *(unsigned long long*)&xlds[row * 136 + k4] = pk;
        }
    }
    __syncthreads();

    const int wv   = t >> 6;     // wave 0..1 -> rows [16wv, 16wv+16)
    const int lane = t & 63;
    const int m    = lane & 15;  // row (A) / col (B,C)
    const int kg   = lane >> 4;  // k-group 0..3

    f32x4 acc[8] = {};
#pragma unroll
    for (int s = 0; s < 4; ++s) {
        const int k = s * 32 + kg * 8;
        s16x8 a = *(const s16x8*)&xlds[(wv * 16 + m) * 136 + k];
#pragma unroll
        for (int j0 = 0; j0 < 8; ++j0) {
            const int n = j0 * 16 + m;
            const int byte = n * 256 + k * 2;
            const int swz = byte ^ ((n & 7) << 4);
            s16x8 b = *(const s16x8*)((const char*)wlds + swz);
            acc[j0] = __builtin_amdgcn_mfma_f32_16x16x32_bf16(a, b, acc[j0], 0, 0, 0);
        }
    }

    // C/D layout: col = lane&15, row = (lane>>4)*4 + reg   [m89-verified]
#pragma unroll
    for (int reg = 0; reg < 4; ++reg) {
        const int r = row0 + wv * 16 + kg * 4 + reg;
        const float sd = dis[r];
#pragma unroll
        for (int j0 = 0; j0 < 8; ++j0) {
            hs[(size_t)r * C + j0 * 16 + m] = f2bf(acc[j0][reg] * sd);
        }
    }
}

// one wave per node; lane owns one dword = 2 bf16 cols. Fused epilogue.
__global__ __launch_bounds__(256) void k_gather(const int* __restrict__ rowptr,
                                                const int* __restrict__ adj,
                                                const unsigned int* __restrict__ hsu,
                                                const float* __restrict__ dis,
                                                const float* __restrict__ b,
                                                const float* __restrict__ alpha,
                                                float* __restrict__ out) {
    const int d = (blockIdx.x * 256 + threadIdx.x) >> 6;
    const int lane = threadIdx.x & 63;
    if (d >= N_NODES) return;
    const int beg = rowptr[d], end = rowptr[d + 1];

    float ax, ay;
    {   // self-loop term
        unsigned int u = hsu[(size_t)d * 64 + lane];
        ax = __uint_as_float(u << 16);
        ay = __uint_as_float(u & 0xffff0000u);
    }
    int j = beg;
    for (; j + 3 < end; j += 4) {   // unroll-4 for MLP
        int s0 = adj[j], s1 = adj[j + 1], s2 = adj[j + 2], s3 = adj[j + 3];
        unsigned int u0 = hsu[(size_t)s0 * 64 + lane];
        unsigned int u1 = hsu[(size_t)s1 * 64 + lane];
        unsigned int u2 = hsu[(size_t)s2 * 64 + lane];
        unsigned int u3 = hsu[(size_t)s3 * 64 + lane];
        ax += __uint_as_float(u0 << 16); ay += __uint_as_float(u0 & 0xffff0000u);
        ax += __uint_as_float(u1 << 16); ay += __uint_as_float(u1 & 0xffff0000u);
        ax += __uint_as_float(u2 << 16); ay += __uint_as_float(u2 & 0xffff0000u);
        ax += __uint_as_float(u3 << 16); ay += __uint_as_float(u3 & 0xffff0000u);
    }
    for (; j < end; ++j) {
        unsigned int u = hsu[(size_t)adj[j] * 64 + lane];
        ax += __uint_as_float(u << 16); ay += __uint_as_float(u & 0xffff0000u);
    }

    const float sd = dis[d];
    const float a  = alpha[0];
    float2 bv = *(const float2*)&b[lane * 2];
    float t0 = fmaf(ax, sd, bv.x);
    float t1 = fmaf(ay, sd, bv.y);
    float2 r;
    r.x = t0 >= 0.f ? t0 : a * t0;
    r.y = t1 >= 0.f ? t1 : a * t1;
    *(float2*)&out[(size_t)d * C + lane * 2] = r;
}

extern "C" void kernel_launch(void* const* d_in, const int* in_sizes, int n_in,
                              void* d_out, int out_size, void* d_ws, size_t ws_size,
                              hipStream_t stream) {
    const float* x     = (const float*)d_in[0];
    const int*   ei    = (const int*)d_in[1];     // [2][E] flat: row0=src, row1=dst
    const float* W     = (const float*)d_in[2];
    const float* b     = (const float*)d_in[3];
    const float* alpha = (const float*)d_in[4];
    float* out = (float*)d_out;

    const int* src = ei;
    const int* dst = ei + N_EDGES;

    // workspace layout (all 4B-aligned)
    char* p = (char*)d_ws;
    int*   cnt    = (int*)p;                 p += sizeof(int) * N_NODES;
    int*   rowptr = (int*)p;                 p += sizeof(int) * (N_NODES + 1);
    int*   cursor = (int*)p;                 p += sizeof(int) * N_NODES;
    int*   bsum   = (int*)p;                 p += sizeof(int) * 512;
    float* dis    = (float*)p;               p += sizeof(float) * N_NODES;
    int*   adj    = (int*)p;                 p += sizeof(int) * N_EDGES;
    unsigned short* Wt = (unsigned short*)p; p += sizeof(unsigned short) * C * C;
    unsigned short* hs = (unsigned short*)p; // N*C bf16 (25.6 MB)

    const int gN = (N_NODES + 255) / 256;
    const int gE = (N_EDGES + 255) / 256;

    k_zero <<<gN, 256, 0, stream>>>(cnt);
    k_count<<<gE, 256, 0, stream>>>(dst, cnt);
    k_prep <<<64, 256, 0, stream>>>(W, Wt);
    k_scan1<<<N_BLKS, SCAN_B, 0, stream>>>(cnt, rowptr, bsum);
    k_scan2<<<1, 512, 0, stream>>>(bsum);
    k_scan3<<<N_BLKS, SCAN_B, 0, stream>>>(rowptr, bsum, cursor, cnt, dis);
    k_fill <<<gE, 256, 0, stream>>>(src, dst, cursor, adj);
    k_gemm <<<N_NODES / BM, 128, 0, stream>>>(x, Wt, dis, hs);
    k_gather<<<(N_NODES * 64 + 255) / 256, 256, 0, stream>>>(rowptr, adj,
                                                             (const unsigned int*)hs,
                                                             dis, b, alpha, out);
}

// Round 17
// 264.634 us; speedup vs baseline: 11.0717x; 1.4560x over previous
//
#include <hip/hip_runtime.h>

// GCNConv (self-loops, symmetric norm) + bias + PReLU.
// out[d] = prelu( dis[d] * ( sum_{e: dst=d} hs[src_e] + hs[d] ) + b )
// hs = bf16( (x @ W) * dis[row] ) via MFMA; dis = rsqrt(deg+1).
// CSR build via two-level binned counting sort (coalesced writes, few atomics).

constexpr int N_NODES = 100000;
constexpr int N_EDGES = 1600000;
constexpr int C  = 128;
constexpr int BM = 32;                        // GEMM row tile
constexpr int NBUCK  = (N_NODES + 127) >> 7;  // 782 coarse buckets (128 nodes each)
constexpr int BCHUNK = 8192;                  // edges per block in phase A
constexpr int ABLKS  = (N_EDGES + BCHUNK - 1) / BCHUNK;   // 196
constexpr int BCAP   = 3072;                  // max edges per bucket (mean 2048, sigma 45)

using f32x4 = __attribute__((ext_vector_type(4))) float;
using s16x8 = __attribute__((ext_vector_type(8))) short;   // 8 bf16 = 4 VGPRs

// round-to-nearest-even fp32 -> bf16
__device__ __forceinline__ unsigned short f2bf(float f) {
    unsigned int u = __float_as_uint(f);
    u += 0x7fffu + ((u >> 16) & 1u);
    return (unsigned short)(u >> 16);
}

__global__ __launch_bounds__(1024) void k_zerob(int* __restrict__ bhist) {
    int t = threadIdx.x;
    if (t < NBUCK) bhist[t] = 0;
}

// coarse histogram: one LDS hist per block, one global atomic per (block,bucket)
__global__ __launch_bounds__(256) void k_bhist(const int* __restrict__ dst,
                                               int* __restrict__ bhist) {
    __shared__ int h[NBUCK];
    for (int i = threadIdx.x; i < NBUCK; i += 256) h[i] = 0;
    __syncthreads();
    const int beg = blockIdx.x * BCHUNK;
    const int end = min(beg + BCHUNK, N_EDGES);
    for (int e = beg + threadIdx.x; e < end; e += 256)
        atomicAdd(&h[dst[e] >> 7], 1);
    __syncthreads();
    for (int i = threadIdx.x; i < NBUCK; i += 256)
        if (h[i]) atomicAdd(&bhist[i], h[i]);
}

// exclusive scan of bucket totals -> bbase (and init gcur)
__global__ __launch_bounds__(1024) void k_bscan(const int* __restrict__ bhist,
                                                int* __restrict__ bbase,
                                                int* __restrict__ gcur) {
    __shared__ int s[1024];
    int t = threadIdx.x;
    int v = (t < NBUCK) ? bhist[t] : 0;
    s[t] = v;
    __syncthreads();
#pragma unroll
    for (int off = 1; off < 1024; off <<= 1) {
        int u = (t >= off) ? s[t - off] : 0;
        __syncthreads();
        s[t] += u;
        __syncthreads();
    }
    if (t < NBUCK) { int b = s[t] - v; bbase[t] = b; gcur[t] = b; }
    if (t == 0) bbase[NBUCK] = N_EDGES;
}

// scatter packed (src<<7 | dst&127) into bucket regions; block-private runs
__global__ __launch_bounds__(256) void k_binscatter(const int* __restrict__ src,
                                                    const int* __restrict__ dst,
                                                    int* __restrict__ gcur,
                                                    unsigned int* __restrict__ pairs) {
    __shared__ int h[NBUCK];
    __shared__ int off[NBUCK];
    for (int i = threadIdx.x; i < NBUCK; i += 256) h[i] = 0;
    __syncthreads();
    const int beg = blockIdx.x * BCHUNK;
    const int end = min(beg + BCHUNK, N_EDGES);
    for (int e = beg + threadIdx.x; e < end; e += 256)
        atomicAdd(&h[dst[e] >> 7], 1);
    __syncthreads();
    for (int i = threadIdx.x; i < NBUCK; i += 256)
        off[i] = h[i] ? atomicAdd(&gcur[i], h[i]) : 0;
    __syncthreads();
    for (int e = beg + threadIdx.x; e < end; e += 256) {
        int d = dst[e];
        int bk = d >> 7;
        int pos = atomicAdd(&off[bk], 1);
        pairs[pos] = ((unsigned int)src[e] << 7) | (unsigned int)(d & 127);
    }
}

// per-bucket fine sort in LDS; emits rowptr, dis, and coalesced adj
__global__ __launch_bounds__(256) void k_bucket(const int* __restrict__ bbase,
                                                const unsigned int* __restrict__ pairs,
                                                int* __restrict__ rowptr,
                                                float* __restrict__ dis,
                                                int* __restrict__ adj) {
    __shared__ int h[128];
    __shared__ int excl[128];
    __shared__ int adjl[BCAP];
    const int b = blockIdx.x;
    const int beg = bbase[b], end = bbase[b + 1];
    const int n = end - beg;
    const int t = threadIdx.x;
    if (t < 128) h[t] = 0;
    __syncthreads();
    for (int i = beg + t; i < end; i += 256)
        atomicAdd(&h[pairs[i] & 127u], 1);
    __syncthreads();
    if (t == 0) {
        int acc = 0;
#pragma unroll
        for (int l = 0; l < 128; ++l) { excl[l] = acc; acc += h[l]; }
    }
    __syncthreads();
    if (t < 128) {
        int node = b * 128 + t;
        if (node < N_NODES) {
            rowptr[node] = beg + excl[t];
            dis[node] = rsqrtf((float)(h[t] + 1));
        }
        h[t] = excl[t];    // reuse as cursor
    }
    if (b == 0 && t == 0) rowptr[N_NODES] = N_EDGES;
    __syncthreads();
    for (int i = beg + t; i < end; i += 256) {
        unsigned int p = pairs[i];
        int pos = atomicAdd(&h[p & 127u], 1);
        adjl[pos] = (int)(p >> 7);
    }
    __syncthreads();
    for (int i = t; i < n; i += 256) adj[beg + i] = adjl[i];
}

// Wt[j][k] = bf16(W[k][j])
__global__ __launch_bounds__(256) void k_prep(const float* __restrict__ W,
                                              unsigned short* __restrict__ Wt) {
    int tid = blockIdx.x * 256 + threadIdx.x;   // 64 x 256 = 16384
    int k = tid & 127;
    int j = tid >> 7;
    Wt[j * 128 + k] = f2bf(W[k * 128 + j]);
}

// hs[r][:] = bf16( (x[r][:] @ W) * dis[r] ), MFMA 16x16x32 bf16.
__global__ __launch_bounds__(128) void k_gemm(const float* __restrict__ x,
                                              const unsigned short* __restrict__ Wt,
                                              const float* __restrict__ dis,
                                              unsigned short* __restrict__ hs) {
    __shared__ __align__(16) unsigned short wlds[128 * 128];  // 32 KiB, XOR-swizzled
    __shared__ __align__(16) unsigned short xlds[BM * 136];   // padded rows

    const int t = threadIdx.x;
    {
        const ulonglong2* srcp = (const ulonglong2*)Wt;
#pragma unroll
        for (int i = 0; i < 16; ++i) {
            int c = i * 128 + t;
            int byte = c << 4;
            int row = byte >> 8;
            int dstb = byte ^ ((row & 7) << 4);
            *(ulonglong2*)((char*)wlds + dstb) = srcp[c];
        }
    }
    const int row0 = blockIdx.x * BM;
    {
        const float4* xs4 = (const float4*)(x + (size_t)row0 * C);
#pragma unroll
        for (int i = 0; i < 8; ++i) {
            int c = i * 128 + t;
            float4 v = xs4[c];
            int row = c >> 5;
            int k4  = (c & 31) << 2;
            unsigned long long pk =
                  (unsigned long long)f2bf(v.x)
                | ((unsigned long long)f2bf(v.y) << 16)
                | ((unsigned long long)f2bf(v.z) << 32)
                | ((unsigned long long)f2bf(v.w) << 48);
            *(unsigned long long*)&xlds[row * 136 + k4] = pk;
        }
    }
    __syncthreads();

    const int wv   = t >> 6;
    const int lane = t & 63;
    const int m    = lane & 15;
    const int kg   = lane >> 4;

    f32x4 acc[8] = {};
#pragma unroll
    for (int s = 0; s < 4; ++s) {
        const int k = s * 32 + kg * 8;
        s16x8 a = *(const s16x8*)&xlds[(wv * 16 + m) * 136 + k];
#pragma unroll
        for (int j0 = 0; j0 < 8; ++j0) {
            const int n = j0 * 16 + m;
            const int byte = n * 256 + k * 2;
            const int swz = byte ^ ((n & 7) << 4);
            s16x8 b = *(const s16x8*)((const char*)wlds + swz);
            acc[j0] = __builtin_amdgcn_mfma_f32_16x16x32_bf16(a, b, acc[j0], 0, 0, 0);
        }
    }

#pragma unroll
    for (int reg = 0; reg < 4; ++reg) {
        const int r = row0 + wv * 16 + kg * 4 + reg;
        const float sd = dis[r];
#pragma unroll
        for (int j0 = 0; j0 < 8; ++j0) {
            hs[(size_t)r * C + j0 * 16 + m] = f2bf(acc[j0][reg] * sd);
        }
    }
}

// one wave per node; lane owns one dword = 2 bf16 cols. Fused epilogue.
__global__ __launch_bounds__(256) void k_gather(const int* __restrict__ rowptr,
                                                const int* __restrict__ adj,
                                                const unsigned int* __restrict__ hsu,
                                                const float* __restrict__ dis,
                                                const float* __restrict__ b,
                                                const float* __restrict__ alpha,
                                                float* __restrict__ out) {
    const int d = (blockIdx.x * 256 + threadIdx.x) >> 6;
    const int lane = threadIdx.x & 63;
    if (d >= N_NODES) return;
    const int beg = rowptr[d], end = rowptr[d + 1];

    float ax, ay;
    {
        unsigned int u = hsu[(size_t)d * 64 + lane];
        ax = __uint_as_float(u << 16);
        ay = __uint_as_float(u & 0xffff0000u);
    }
    int j = beg;
    for (; j + 3 < end; j += 4) {
        int s0 = adj[j], s1 = adj[j + 1], s2 = adj[j + 2], s3 = adj[j + 3];
        unsigned int u0 = hsu[(size_t)s0 * 64 + lane];
        unsigned int u1 = hsu[(size_t)s1 * 64 + lane];
        unsigned int u2 = hsu[(size_t)s2 * 64 + lane];
        unsigned int u3 = hsu[(size_t)s3 * 64 + lane];
        ax += __uint_as_float(u0 << 16); ay += __uint_as_float(u0 & 0xffff0000u);
        ax += __uint_as_float(u1 << 16); ay += __uint_as_float(u1 & 0xffff0000u);
        ax += __uint_as_float(u2 << 16); ay += __uint_as_float(u2 & 0xffff0000u);
        ax += __uint_as_float(u3 << 16); ay += __uint_as_float(u3 & 0xffff0000u);
    }
    for (; j < end; ++j) {
        unsigned int u = hsu[(size_t)adj[j] * 64 + lane];
        ax += __uint_as_float(u << 16); ay += __uint_as_float(u & 0xffff0000u);
    }

    const float sd = dis[d];
    const float a  = alpha[0];
    float2 bv = *(const float2*)&b[lane * 2];
    float t0 = fmaf(ax, sd, bv.x);
    float t1 = fmaf(ay, sd, bv.y);
    float2 r;
    r.x = t0 >= 0.f ? t0 : a * t0;
    r.y = t1 >= 0.f ? t1 : a * t1;
    *(float2*)&out[(size_t)d * C + lane * 2] = r;
}

extern "C" void kernel_launch(void* const* d_in, const int* in_sizes, int n_in,
                              void* d_out, int out_size, void* d_ws, size_t ws_size,
                              hipStream_t stream) {
    const float* x     = (const float*)d_in[0];
    const int*   ei    = (const int*)d_in[1];     // [2][E] flat: row0=src, row1=dst
    const float* W     = (const float*)d_in[2];
    const float* b     = (const float*)d_in[3];
    const float* alpha = (const float*)d_in[4];
    float* out = (float*)d_out;

    const int* src = ei;
    const int* dst = ei + N_EDGES;

    // workspace layout (4B-aligned throughout)
    char* p = (char*)d_ws;
    int* bhist = (int*)p;                    p += sizeof(int) * NBUCK;
    int* bbase = (int*)p;                    p += sizeof(int) * (NBUCK + 1);
    int* gcur  = (int*)p;                    p += sizeof(int) * NBUCK;
    int* rowptr = (int*)p;                   p += sizeof(int) * (N_NODES + 1);
    float* dis = (float*)p;                  p += sizeof(float) * N_NODES;
    unsigned int* pairs = (unsigned int*)p;  p += sizeof(unsigned int) * N_EDGES;
    int* adj = (int*)p;                      p += sizeof(int) * N_EDGES;
    unsigned short* Wt = (unsigned short*)p; p += sizeof(unsigned short) * C * C;
    unsigned short* hs = (unsigned short*)p; // N*C bf16 (25.6 MB)

    k_zerob<<<1, 1024, 0, stream>>>(bhist);
    k_bhist<<<ABLKS, 256, 0, stream>>>(dst, bhist);
    k_bscan<<<1, 1024, 0, stream>>>(bhist, bbase, gcur);
    k_binscatter<<<ABLKS, 256, 0, stream>>>(src, dst, gcur, pairs);
    k_bucket<<<NBUCK, 256, 0, stream>>>(bbase, pairs, rowptr, dis, adj);
    k_prep<<<64, 256, 0, stream>>>(W, Wt);
    k_gemm<<<N_NODES / BM, 128, 0, stream>>>(x, Wt, dis, hs);
    k_gather<<<(N_NODES * 64 + 255) / 256, 256, 0, stream>>>(rowptr, adj,
                                                             (const unsigned int*)hs,
                                                             dis, b, alpha, out);
}